// Round 1
// baseline (376.576 us; speedup 1.0000x reference)
//
#include <hip/hip_runtime.h>
#include <hip/hip_bf16.h>

typedef __attribute__((ext_vector_type(4))) float f32x4;
typedef __attribute__((ext_vector_type(16))) float f32x16;
typedef __attribute__((ext_vector_type(8))) short short8;
typedef unsigned short ushort_t;

#define BATCH 256
#define PDIM 512
#define MDIM 768
#define XCOLS 1280
#define PROJ 512
#define HID 256
#define KTOT (PDIM * MDIM)

#define BN 64
#define NT 8        // N tiles (512 / 64)
#define PSPLIT 64   // pi splits
#define PI_PER 8    // 512 / 64
#define NSTEP 96    // PI_PER * 12 j-windows

__device__ __forceinline__ ushort_t f2bf(float f) {
  __hip_bfloat16 h = __float2bfloat16(f);
  return __builtin_bit_cast(ushort_t, h);
}
__device__ __forceinline__ float bf2f(ushort_t u) {
  union { unsigned int i; float f; } c;
  c.i = ((unsigned int)u) << 16;
  return c.f;
}

// ---------------- prep: p transpose + bf16(m) ----------------
__global__ void prep_kernel(const float* __restrict__ x, float* __restrict__ pT,
                            ushort_t* __restrict__ mB) {
  int tid = blockIdx.x * blockDim.x + threadIdx.x;
  int nth = gridDim.x * blockDim.x;
  for (int i = tid; i < PDIM * BATCH; i += nth) {
    int pi = i >> 8, b = i & 255;   // pT[pi][b]
    pT[i] = x[b * XCOLS + pi];
  }
  for (int i = tid; i < BATCH * MDIM; i += nth) {
    int b = i / MDIM, j = i - b * MDIM;   // mB[b][j]
    mB[i] = f2bf(x[b * XCOLS + PDIM + j]);
  }
}

// ---------------- main einsum GEMM ----------------
// C[256,512] partial over pi-range; A synthesized = p (x) m, B = bf16(W1 tile)
__global__ __launch_bounds__(512, 4)
void einsum_kernel(const float* __restrict__ W1, const ushort_t* __restrict__ mB,
                   const float* __restrict__ pT, float* __restrict__ outp,
                   int atomic_mode) {
  // fragment-ordered LDS: [mf][ks][lane][8 bf16]
  __shared__ ushort_t Af[8 * 4 * 64 * 8];  // 32 KB (A: 256x64)
  __shared__ ushort_t Bf[2 * 4 * 64 * 8];  // 8 KB  (B: 64n x 64k)
  __shared__ float pl[PI_PER * BATCH];     // 8 KB

  const int ntile = blockIdx.x & 7;
  const int ps    = blockIdx.x >> 3;      // 0..63
  const int pi0   = ps * PI_PER;
  const int t     = threadIdx.x;
  const int lane  = t & 63;
  const int wave  = t >> 6;               // 8 waves: 4M x 2N
  const int wm    = wave & 3;
  const int wn    = wave >> 2;
  const int n0    = ntile * BN;

  // stage p block for this WG's pi-range (coalesced from pT)
  {
    f32x4 v = ((const f32x4*)(pT + pi0 * BATCH))[t];
    ((f32x4*)pl)[t] = v;
  }
  __syncthreads();

  // staging thread mapping: A: 4 rows x 8 j ; B: 1 n-row x 8 k
  const int srow = (t >> 3) << 2;  // 0..252
  const int sq   = t & 7;          // k-octet
  const int sn   = t >> 3;         // B n index 0..63

  // fragment-order write offsets (ushort units)
  const int bwo    = (((sn >> 5) * 4 + (sq >> 1)) * 64 + (sn & 31) + ((sq & 1) << 5)) * 8;
  const int awbase = (((srow >> 5) * 4 + (sq >> 1)) * 64 + (srow & 31) + ((sq & 1) << 5)) * 8;

  f32x16 acc0, acc1;
#pragma unroll
  for (int i = 0; i < 16; ++i) { acc0[i] = 0.f; acc1[i] = 0.f; }

  const ushort_t* mrow = mB + srow * MDIM;
  const float* wbase = W1 + (size_t)(n0 + sn) * KTOT + sq * 8;

  for (int s = 0; s < NSTEP; ++s) {
    const int pil = s / 12;
    const int jw  = s - pil * 12;
    const int kkb = (pi0 + pil) * MDIM + jw * 64;

    // ---- STAGE: global loads first (HBM W1, then L1/L2 m), then cvt+LDS ----
    const float* wp = wbase + kkb;
    f32x4 wv0 = *(const f32x4*)wp;
    f32x4 wv1 = *(const f32x4*)(wp + 4);

    const ushort_t* mp = mrow + jw * 64 + sq * 8;
    short8 m0 = *(const short8*)(mp);
    short8 m1 = *(const short8*)(mp + MDIM);
    short8 m2 = *(const short8*)(mp + 2 * MDIM);
    short8 m3 = *(const short8*)(mp + 3 * MDIM);

    const float* pp = pl + pil * BATCH + srow;
    float p0 = pp[0], p1 = pp[1], p2 = pp[2], p3 = pp[3];

    // B tile -> bf16, fragment order
    short8 bs;
#pragma unroll
    for (int i = 0; i < 4; ++i) {
      bs[i]     = (short)f2bf(wv0[i]);
      bs[i + 4] = (short)f2bf(wv1[i]);
    }
    *(short8*)&Bf[bwo] = bs;

    // A tile: a = bf16(p * m), fragment order
    short8 a0, a1, a2, a3;
#pragma unroll
    for (int i = 0; i < 8; ++i) {
      a0[i] = (short)f2bf(p0 * bf2f((ushort_t)m0[i]));
      a1[i] = (short)f2bf(p1 * bf2f((ushort_t)m1[i]));
      a2[i] = (short)f2bf(p2 * bf2f((ushort_t)m2[i]));
      a3[i] = (short)f2bf(p3 * bf2f((ushort_t)m3[i]));
    }
    *(short8*)&Af[awbase]      = a0;
    *(short8*)&Af[awbase + 8]  = a1;
    *(short8*)&Af[awbase + 16] = a2;
    *(short8*)&Af[awbase + 24] = a3;

    __syncthreads();

    // ---- MFMA phase ----
    const short8* Afv = (const short8*)Af;
    const short8* Bfv = (const short8*)Bf;
    const int a0b = ((wm * 2 + 0) * 4) * 64 + lane;
    const int a1b = ((wm * 2 + 1) * 4) * 64 + lane;
    const int bb  = (wn * 4) * 64 + lane;
#pragma unroll
    for (int ks = 0; ks < 4; ++ks) {
      short8 av0 = Afv[a0b + ks * 64];
      short8 av1 = Afv[a1b + ks * 64];
      short8 bv  = Bfv[bb + ks * 64];
      acc0 = __builtin_amdgcn_mfma_f32_32x32x16_bf16(av0, bv, acc0, 0, 0, 0);
      acc1 = __builtin_amdgcn_mfma_f32_32x32x16_bf16(av1, bv, acc1, 0, 0, 0);
    }
    __syncthreads();
  }

  // ---- epilogue: C layout col=lane&31, row=(r&3)+8*(r>>2)+4*(lane>>5) ----
  const int col   = n0 + wn * 32 + (lane & 31);
  const int rbase = wm * 64 + ((lane >> 5) << 2);
  if (atomic_mode) {
#pragma unroll
    for (int r = 0; r < 16; ++r) {
      int row = rbase + (r & 3) + ((r >> 2) << 3);
      atomicAdd(&outp[(size_t)row * PROJ + col], acc0[r]);
      atomicAdd(&outp[(size_t)(row + 32) * PROJ + col], acc1[r]);
    }
  } else {
    float* dst = outp + (size_t)ps * BATCH * PROJ;
#pragma unroll
    for (int r = 0; r < 16; ++r) {
      int row = rbase + (r & 3) + ((r >> 2) << 3);
      dst[(size_t)row * PROJ + col] = acc0[r];
      dst[(size_t)(row + 32) * PROJ + col] = acc1[r];
    }
  }
}

// ---------------- reduce + LN + MLP ----------------
__global__ __launch_bounds__(256)
void mlp_kernel(const float* __restrict__ part, int nps,
                const float* __restrict__ b1, const float* __restrict__ lng,
                const float* __restrict__ lnb, const float* __restrict__ W2,
                const float* __restrict__ b2, const float* __restrict__ g1,
                const float* __restrict__ bb1, const float* __restrict__ W3,
                const float* __restrict__ b3, const float* __restrict__ g2,
                const float* __restrict__ bb2, const float* __restrict__ W4,
                const float* __restrict__ b4, float* __restrict__ out) {
  __shared__ float h1[PROJ];
  __shared__ float h2[HID];
  __shared__ float h3[HID / 2];
  __shared__ float red[16];
  const int b = blockIdx.x, t = threadIdx.x;

  // sum split-K partials
  float f0 = 0.f, f1 = 0.f;
  const float* p0 = part + (size_t)b * PROJ + t;
#pragma unroll 4
  for (int s = 0; s < nps; ++s) {
    f0 += p0[0];
    f1 += p0[256];
    p0 += (size_t)BATCH * PROJ;
  }
  f0 += b1[t];
  f1 += b1[t + 256];

  // LayerNorm over 512
  float sum = f0 + f1, ss = f0 * f0 + f1 * f1;
#pragma unroll
  for (int o = 32; o > 0; o >>= 1) {
    sum += __shfl_xor(sum, o);
    ss  += __shfl_xor(ss, o);
  }
  const int wv = t >> 6, ln = t & 63;
  if (ln == 0) { red[wv] = sum; red[8 + wv] = ss; }
  __syncthreads();
  sum = red[0] + red[1] + red[2] + red[3];
  ss  = red[8] + red[9] + red[10] + red[11];
  float mu   = sum * (1.f / 512.f);
  float var  = ss * (1.f / 512.f) - mu * mu;
  float rstd = rsqrtf(var + 1e-5f);
  h1[t]       = fmaxf(0.f, (f0 - mu) * rstd * lng[t] + lnb[t]);
  h1[t + 256] = fmaxf(0.f, (f1 - mu) * rstd * lng[t + 256] + lnb[t + 256]);
  __syncthreads();

  const float bninv = rsqrtf(1.f + 1e-5f);
  // layer 2: 512 -> 256
  {
    const f32x4* wr = (const f32x4*)(W2 + (size_t)t * PROJ);
    const f32x4* hv = (const f32x4*)h1;
    float a = 0.f;
#pragma unroll 4
    for (int i = 0; i < PROJ / 4; ++i) {
      f32x4 w = wr[i], h = hv[i];
      a += w[0] * h[0] + w[1] * h[1] + w[2] * h[2] + w[3] * h[3];
    }
    h2[t] = fmaxf(0.f, (a + b2[t]) * bninv * g1[t] + bb1[t]);
  }
  __syncthreads();
  // layer 3: 256 -> 128
  if (t < 128) {
    const f32x4* wr = (const f32x4*)(W3 + (size_t)t * HID);
    const f32x4* hv = (const f32x4*)h2;
    float a = 0.f;
#pragma unroll 4
    for (int i = 0; i < HID / 4; ++i) {
      f32x4 w = wr[i], h = hv[i];
      a += w[0] * h[0] + w[1] * h[1] + w[2] * h[2] + w[3] * h[3];
    }
    h3[t] = fmaxf(0.f, (a + b3[t]) * bninv * g2[t] + bb2[t]);
  }
  __syncthreads();
  // layer 4: 128 -> 2
  if (t < 2) {
    const float* wr = W4 + t * 128;
    float a = 0.f;
#pragma unroll 4
    for (int i = 0; i < 128; ++i) a += wr[i] * h3[i];
    out[b * 2 + t] = a + b4[t];
  }
}

extern "C" void kernel_launch(void* const* d_in, const int* in_sizes, int n_in,
                              void* d_out, int out_size, void* d_ws, size_t ws_size,
                              hipStream_t stream) {
  const float* x   = (const float*)d_in[0];
  const float* W1  = (const float*)d_in[1];
  const float* b1  = (const float*)d_in[2];
  const float* lng = (const float*)d_in[3];
  const float* lnb = (const float*)d_in[4];
  const float* W2  = (const float*)d_in[5];
  const float* b2  = (const float*)d_in[6];
  const float* g1  = (const float*)d_in[7];
  const float* bb1 = (const float*)d_in[8];
  const float* W3  = (const float*)d_in[9];
  const float* b3  = (const float*)d_in[10];
  const float* g2  = (const float*)d_in[11];
  const float* bb2 = (const float*)d_in[12];
  const float* W4  = (const float*)d_in[13];
  const float* b4  = (const float*)d_in[14];
  float* out = (float*)d_out;

  char* ws = (char*)d_ws;
  float* pT     = (float*)ws;                   // 512 KB
  ushort_t* mBp = (ushort_t*)(ws + 524288);     // 384 KB
  float* big    = (float*)(ws + 1048576);       // partials or fused

  size_t need = 1048576 + (size_t)PSPLIT * BATCH * PROJ * 4;
  bool partial = ws_size >= need;

  hipLaunchKernelGGL(prep_kernel, dim3(256), dim3(256), 0, stream, x, pT, mBp);
  if (partial) {
    hipLaunchKernelGGL(einsum_kernel, dim3(NT * PSPLIT), dim3(512), 0, stream,
                       W1, mBp, pT, big, 0);
    hipLaunchKernelGGL(mlp_kernel, dim3(BATCH), dim3(256), 0, stream, big, PSPLIT,
                       b1, lng, lnb, W2, b2, g1, bb1, W3, b3, g2, bb2, W4, b4, out);
  } else {
    hipMemsetAsync(big, 0, (size_t)BATCH * PROJ * 4, stream);
    hipLaunchKernelGGL(einsum_kernel, dim3(NT * PSPLIT), dim3(512), 0, stream,
                       W1, mBp, pT, big, 1);
    hipLaunchKernelGGL(mlp_kernel, dim3(BATCH), dim3(256), 0, stream, big, 1,
                       b1, lng, lnb, W2, b2, g1, bb1, W3, b3, g2, bb2, W4, b4, out);
  }
}

// Round 2
// 233.966 us; speedup vs baseline: 1.6095x; 1.6095x over previous
//
#include <hip/hip_runtime.h>
#include <hip/hip_bf16.h>

typedef __attribute__((ext_vector_type(4))) float f32x4;
typedef __attribute__((ext_vector_type(16))) float f32x16;
typedef __attribute__((ext_vector_type(8))) short short8;
typedef unsigned short ushort_t;

#define BATCH 256
#define PDIM 512
#define MDIM 768
#define XCOLS 1280
#define PROJ 512
#define HID 256
#define KTOT (PDIM * MDIM)

#define BN 64
#define NT 8        // N tiles (512/64)
#define PSPLIT 64   // pi splits
#define PI_PER 8    // 512/64
#define NJW 12      // j windows of 64
#define NSTEPS 96   // PI_PER * NJW

__device__ __forceinline__ ushort_t f2bf(float f) {
  __hip_bfloat16 h = __float2bfloat16(f);
  return __builtin_bit_cast(ushort_t, h);
}

// ---------------- prep: p transpose + fragment-ordered bf16(m) ----------------
// mF layout: chunk c = ((jw*8+mf)*4+ks)*64+lane, 8 bf16 per chunk:
//   element e of chunk = bf16( m[row = mf*32+(lane&31)][k = jw*64+ks*16+(lane>>5)*8+e] )
__global__ void prep_kernel(const float* __restrict__ x, float* __restrict__ pT,
                            ushort_t* __restrict__ mF) {
  int tid = blockIdx.x * blockDim.x + threadIdx.x;
  int nth = gridDim.x * blockDim.x;
  for (int i = tid; i < PDIM * BATCH; i += nth) {
    int pi = i >> 8, b = i & 255;   // pT[pi][b]
    pT[i] = x[b * XCOLS + pi];
  }
  for (int c = tid; c < NJW * 8 * 4 * 64; c += nth) {
    int lane = c & 63;
    int ks = (c >> 6) & 3;
    int mf = (c >> 8) & 7;
    int jw = c >> 11;
    int row = mf * 32 + (lane & 31);
    int k0 = jw * 64 + ks * 16 + ((lane >> 5) << 3);
    const float* src = x + row * XCOLS + PDIM + k0;
    f32x4 v0 = *(const f32x4*)src;
    f32x4 v1 = *(const f32x4*)(src + 4);
    short8 o;
#pragma unroll
    for (int i = 0; i < 4; ++i) {
      o[i] = (short)f2bf(v0[i]);
      o[i + 4] = (short)f2bf(v1[i]);
    }
    ((short8*)mF)[c] = o;
  }
}

// ---------------- main einsum GEMM ----------------
// fused[b, n] partial over this WG's pi range; A = bf16(m) (pi-invariant),
// p-scale applied per (jw,pil) to the f32 MFMA accumulator.
__global__ __launch_bounds__(512, 4)
void einsum_kernel(const float* __restrict__ W1, const ushort_t* __restrict__ mF,
                   const float* __restrict__ pT, float* __restrict__ outp,
                   int atomic_mode) {
  __shared__ ushort_t Af[16384];     // 32 KB: A frags for current jw
  __shared__ ushort_t Bf[2][4096];   // 2 x 8 KB: B frags, double-buffered
  __shared__ float pl[PI_PER * BATCH]; // 8 KB: p[pil][b]

  const int ntile = blockIdx.x & 7;
  const int ps    = blockIdx.x >> 3;
  const int pi0   = ps * PI_PER;
  const int n0    = ntile * BN;
  const int t     = threadIdx.x;
  const int lane  = t & 63;
  const int wave  = t >> 6;   // 8 waves: 4M x 2N
  const int wm    = wave & 3;
  const int wn    = wave >> 2;

  // stage p for this WG's pi range (visible after first barrier)
  ((f32x4*)pl)[t] = ((const f32x4*)(pT + pi0 * BATCH))[t];

  // B staging mapping: thread (sn = t>>3 in 0..63, sq = t&7) handles
  // B[n=sn][k=sq*8..+8] -> frag (nf=sn>>5, ks=sq>>1, lane=(sn&31)+32*(sq&1))
  const int sn = t >> 3, sq = t & 7;
  const int bofs = (((sn >> 5) * 4 + (sq >> 1)) * 64 + (sn & 31) + ((sq & 1) << 5)) * 8;
  const float* wbase = W1 + (size_t)(n0 + sn) * KTOT + sq * 8;

  // fragment read indices (short8 units)
  const int aidx0 = wm * 512 + lane;          // mf = wm*2
  const int aidx1 = aidx0 + 256;              // mf = wm*2+1
  const int bidx  = wn * 256 + lane;          // nf = wn

  f32x16 fa0, fa1;
#pragma unroll
  for (int i = 0; i < 16; ++i) { fa0[i] = 0.f; fa1[i] = 0.f; }
  f32x16 zz;
#pragma unroll
  for (int i = 0; i < 16; ++i) zz[i] = 0.f;

  // prologue: issue B(0) loads (pil=0, jw=0)
  f32x4 c0, c1, nv0, nv1;
  {
    const float* wp = wbase + (size_t)pi0 * MDIM;
    c0 = *(const f32x4*)wp;
    c1 = *(const f32x4*)(wp + 4);
  }

  const short8* AfV = (const short8*)Af;

  for (int s = 0; s < NSTEPS; ++s) {
    const int pil = s & 7;
    const int jw  = s >> 3;
    const bool boundary = (pil == 0);

    if (!boundary) {
      // issue B(s+1): compiler keeps these in flight; waitcnt lands at cvt use
      const int s1 = s + 1;
      const float* wp = wbase + (size_t)(pi0 + (s1 & 7)) * MDIM + (s1 >> 3) * 64;
      nv0 = *(const f32x4*)wp;
      nv1 = *(const f32x4*)(wp + 4);
    }

    // cvt + write B(s) into Bf[s&1]
    {
      short8 bs;
#pragma unroll
      for (int i = 0; i < 4; ++i) {
        bs[i]     = (short)f2bf(c0[i]);
        bs[i + 4] = (short)f2bf(c1[i]);
      }
      *(short8*)(&Bf[s & 1][bofs]) = bs;
    }
    asm volatile("s_waitcnt lgkmcnt(0)" ::: "memory");
    __builtin_amdgcn_s_barrier();
    asm volatile("" ::: "memory");

    if (boundary) {
      // all waves' reads of the old A tile retired before this barrier;
      // stage A(jw) (pure copy, already fragment-ordered) and issue B(s+1)
      const short8* srcA = (const short8*)(mF + jw * 16384);
      short8 a0 = srcA[t * 4 + 0];
      short8 a1 = srcA[t * 4 + 1];
      short8 a2 = srcA[t * 4 + 2];
      short8 a3 = srcA[t * 4 + 3];
      {
        const int s1 = s + 1;  // pil=1, same jw
        const float* wp = wbase + (size_t)(pi0 + (s1 & 7)) * MDIM + (s1 >> 3) * 64;
        nv0 = *(const f32x4*)wp;
        nv1 = *(const f32x4*)(wp + 4);
      }
      ((short8*)Af)[t * 4 + 0] = a0;
      ((short8*)Af)[t * 4 + 1] = a1;
      ((short8*)Af)[t * 4 + 2] = a2;
      ((short8*)Af)[t * 4 + 3] = a3;
      asm volatile("s_waitcnt lgkmcnt(0)" ::: "memory");
      __builtin_amdgcn_s_barrier();
      asm volatile("" ::: "memory");
    }

    // ---- MFMA phase: acc_pi = m-tile @ W-tile over k=64 ----
    const short8* BfV = (const short8*)Bf[s & 1];
    f32x16 ap0, ap1;
    {
      short8 av0 = AfV[aidx0];
      short8 av1 = AfV[aidx1];
      short8 bv  = BfV[bidx];
      ap0 = __builtin_amdgcn_mfma_f32_32x32x16_bf16(av0, bv, zz, 0, 0, 0);
      ap1 = __builtin_amdgcn_mfma_f32_32x32x16_bf16(av1, bv, zz, 0, 0, 0);
    }
#pragma unroll
    for (int ks = 1; ks < 4; ++ks) {
      short8 av0 = AfV[aidx0 + ks * 64];
      short8 av1 = AfV[aidx1 + ks * 64];
      short8 bv  = BfV[bidx + ks * 64];
      ap0 = __builtin_amdgcn_mfma_f32_32x32x16_bf16(av0, bv, ap0, 0, 0, 0);
      ap1 = __builtin_amdgcn_mfma_f32_32x32x16_bf16(av1, bv, ap1, 0, 0, 0);
    }

    // ---- p-scale epilogue: fused += p[row, pi0+pil] * acc_pi ----
    {
      const float* prow = pl + pil * BATCH;
      const int rb = wm * 64 + ((lane >> 5) << 2);
#pragma unroll
      for (int q = 0; q < 4; ++q) {
        f32x4 p0 = *(const f32x4*)(prow + rb + 8 * q);
        f32x4 p1 = *(const f32x4*)(prow + rb + 32 + 8 * q);
#pragma unroll
        for (int j = 0; j < 4; ++j) {
          fa0[q * 4 + j] += p0[j] * ap0[q * 4 + j];
          fa1[q * 4 + j] += p1[j] * ap1[q * 4 + j];
        }
      }
    }

    c0 = nv0; c1 = nv1;
  }

  // ---- C write: row = mf*32 + (r&3)+8*(r>>2)+4*(lane>>5), col = lane&31 ----
  const int col   = n0 + wn * 32 + (lane & 31);
  const int rbase = wm * 64 + ((lane >> 5) << 2);
  if (atomic_mode) {
#pragma unroll
    for (int r = 0; r < 16; ++r) {
      int row = rbase + (r & 3) + ((r >> 2) << 3);
      atomicAdd(&outp[(size_t)row * PROJ + col], fa0[r]);
      atomicAdd(&outp[(size_t)(row + 32) * PROJ + col], fa1[r]);
    }
  } else {
    float* dst = outp + (size_t)ps * BATCH * PROJ;
#pragma unroll
    for (int r = 0; r < 16; ++r) {
      int row = rbase + (r & 3) + ((r >> 2) << 3);
      dst[(size_t)row * PROJ + col] = fa0[r];
      dst[(size_t)(row + 32) * PROJ + col] = fa1[r];
    }
  }
}

// ---------------- reduce + LN + MLP ----------------
__global__ __launch_bounds__(256)
void mlp_kernel(const float* __restrict__ part, int nps,
                const float* __restrict__ b1, const float* __restrict__ lng,
                const float* __restrict__ lnb, const float* __restrict__ W2,
                const float* __restrict__ b2, const float* __restrict__ g1,
                const float* __restrict__ bb1, const float* __restrict__ W3,
                const float* __restrict__ b3, const float* __restrict__ g2,
                const float* __restrict__ bb2, const float* __restrict__ W4,
                const float* __restrict__ b4, float* __restrict__ out) {
  __shared__ float h1[PROJ];
  __shared__ float h2[HID];
  __shared__ float h3[HID / 2];
  __shared__ float red[16];
  const int b = blockIdx.x, t = threadIdx.x;

  float f0 = 0.f, f1 = 0.f;
  const float* p0 = part + (size_t)b * PROJ + t;
#pragma unroll 4
  for (int s = 0; s < nps; ++s) {
    f0 += p0[0];
    f1 += p0[256];
    p0 += (size_t)BATCH * PROJ;
  }
  f0 += b1[t];
  f1 += b1[t + 256];

  float sum = f0 + f1, ss = f0 * f0 + f1 * f1;
#pragma unroll
  for (int o = 32; o > 0; o >>= 1) {
    sum += __shfl_xor(sum, o);
    ss  += __shfl_xor(ss, o);
  }
  const int wv = t >> 6, ln = t & 63;
  if (ln == 0) { red[wv] = sum; red[8 + wv] = ss; }
  __syncthreads();
  sum = red[0] + red[1] + red[2] + red[3];
  ss  = red[8] + red[9] + red[10] + red[11];
  float mu   = sum * (1.f / 512.f);
  float var  = ss * (1.f / 512.f) - mu * mu;
  float rstd = rsqrtf(var + 1e-5f);
  h1[t]       = fmaxf(0.f, (f0 - mu) * rstd * lng[t] + lnb[t]);
  h1[t + 256] = fmaxf(0.f, (f1 - mu) * rstd * lng[t + 256] + lnb[t + 256]);
  __syncthreads();

  const float bninv = rsqrtf(1.f + 1e-5f);
  {
    const f32x4* wr = (const f32x4*)(W2 + (size_t)t * PROJ);
    const f32x4* hv = (const f32x4*)h1;
    float a = 0.f;
#pragma unroll 4
    for (int i = 0; i < PROJ / 4; ++i) {
      f32x4 w = wr[i], h = hv[i];
      a += w[0] * h[0] + w[1] * h[1] + w[2] * h[2] + w[3] * h[3];
    }
    h2[t] = fmaxf(0.f, (a + b2[t]) * bninv * g1[t] + bb1[t]);
  }
  __syncthreads();
  if (t < 128) {
    const f32x4* wr = (const f32x4*)(W3 + (size_t)t * HID);
    const f32x4* hv = (const f32x4*)h2;
    float a = 0.f;
#pragma unroll 4
    for (int i = 0; i < HID / 4; ++i) {
      f32x4 w = wr[i], h = hv[i];
      a += w[0] * h[0] + w[1] * h[1] + w[2] * h[2] + w[3] * h[3];
    }
    h3[t] = fmaxf(0.f, (a + b3[t]) * bninv * g2[t] + bb2[t]);
  }
  __syncthreads();
  if (t < 2) {
    const float* wr = W4 + t * 128;
    float a = 0.f;
#pragma unroll 4
    for (int i = 0; i < 128; ++i) a += wr[i] * h3[i];
    out[b * 2 + t] = a + b4[t];
  }
}

extern "C" void kernel_launch(void* const* d_in, const int* in_sizes, int n_in,
                              void* d_out, int out_size, void* d_ws, size_t ws_size,
                              hipStream_t stream) {
  const float* x   = (const float*)d_in[0];
  const float* W1  = (const float*)d_in[1];
  const float* b1  = (const float*)d_in[2];
  const float* lng = (const float*)d_in[3];
  const float* lnb = (const float*)d_in[4];
  const float* W2  = (const float*)d_in[5];
  const float* b2  = (const float*)d_in[6];
  const float* g1  = (const float*)d_in[7];
  const float* bb1 = (const float*)d_in[8];
  const float* W3  = (const float*)d_in[9];
  const float* b3  = (const float*)d_in[10];
  const float* g2  = (const float*)d_in[11];
  const float* bb2 = (const float*)d_in[12];
  const float* W4  = (const float*)d_in[13];
  const float* b4  = (const float*)d_in[14];
  float* out = (float*)d_out;

  char* ws = (char*)d_ws;
  float* pT    = (float*)ws;                 // 512 KB
  ushort_t* mF = (ushort_t*)(ws + 524288);   // 384 KB (fragment-ordered bf16 m)
  float* big   = (float*)(ws + 1048576);     // split-K partials

  size_t need = 1048576 + (size_t)PSPLIT * BATCH * PROJ * 4;
  bool partial = ws_size >= need;

  hipLaunchKernelGGL(prep_kernel, dim3(512), dim3(256), 0, stream, x, pT, mF);
  if (partial) {
    hipLaunchKernelGGL(einsum_kernel, dim3(NT * PSPLIT), dim3(512), 0, stream,
                       W1, mF, pT, big, 0);
    hipLaunchKernelGGL(mlp_kernel, dim3(BATCH), dim3(256), 0, stream, big, PSPLIT,
                       b1, lng, lnb, W2, b2, g1, bb1, W3, b3, g2, bb2, W4, b4, out);
  } else {
    hipMemsetAsync(big, 0, (size_t)BATCH * PROJ * 4, stream);
    hipLaunchKernelGGL(einsum_kernel, dim3(NT * PSPLIT), dim3(512), 0, stream,
                       W1, mF, pT, big, 1);
    hipLaunchKernelGGL(mlp_kernel, dim3(BATCH), dim3(256), 0, stream, big, 1,
                       b1, lng, lnb, W2, b2, g1, bb1, W3, b3, g2, bb2, W4, b4, out);
  }
}